// Round 1
// baseline (516.844 us; speedup 1.0000x reference)
//
#include <hip/hip_runtime.h>
#include <hip/hip_bf16.h>

// MoE PHM MLP, MI355X. B=2,S=2048,D=1024 -> T=4096 tokens; E=8, N=4, HID=4096.
// Pipeline: router(f64 logits) -> scan/aux -> gather(bf16) -> materialize
// W_eff = sum_i A_i (x) S_i in bf16 -> per-expert MFMA GEMM fc (+leaky^2) ->
// per-expert MFMA GEMM proj (+scatter to out).
//
// Workspace layout (needs ~178.2 MiB):
//   [0,64MiB)          W_fc   bf16 [E][4096][1024]
//   [64,128MiB)        W_proj bf16 [E][1024][4096]
//   xg   bf16 [5120][1024]  (gathered tokens, 128-padded per expert)
//   h    bf16 [5120][4096]
//   probs f32 [T][8], eidx int[T], tok int[5120], counts/slotctr/offsets int[8]

#define T_TOK 4096
#define DIM   1024
#define NEXP  8
#define HIDD  4096
#define SLOTS 5120

static constexpr size_t OFF_WFC   = 0;
static constexpr size_t OFF_WPROJ = 67108864ull;
static constexpr size_t OFF_XG    = 134217728ull;
static constexpr size_t OFF_H     = 144703488ull;
static constexpr size_t OFF_PROBS = 186646528ull;
static constexpr size_t OFF_EIDX  = OFF_PROBS + (size_t)T_TOK*8*4;   // 186777600
static constexpr size_t OFF_TOK   = OFF_EIDX + (size_t)T_TOK*4;      // 186793984
static constexpr size_t OFF_CNT   = OFF_TOK + (size_t)SLOTS*4;       // 186814464

typedef __attribute__((ext_vector_type(8))) short short8;
typedef __attribute__((ext_vector_type(4))) float f32x4;

static __device__ __forceinline__ ushort f2bf(float f) {
    __hip_bfloat16 h = __float2bfloat16(f);
    return __builtin_bit_cast(ushort, h);
}

static __device__ __forceinline__ void gload_lds16(const ushort* g, ushort* l) {
    __builtin_amdgcn_global_load_lds((const __attribute__((address_space(1))) void*)g,
                                     (__attribute__((address_space(3))) void*)l,
                                     16, 0, 0);
}

// ---------------- router: f64 logits, softmax probs, argmax, counts ----------
__global__ __launch_bounds__(256) void router_k(const float* __restrict__ x,
                                                const float* __restrict__ wr,
                                                float* __restrict__ probs,
                                                int* __restrict__ eidx,
                                                int* __restrict__ counts)
{
    int tid = threadIdx.x, w = tid >> 6, lane = tid & 63;
    int t = blockIdx.x * 4 + w;
    const float4* xr = (const float4*)(x + (size_t)t * DIM);
    float4 xv[4];
#pragma unroll
    for (int q = 0; q < 4; q++) xv[q] = xr[q * 64 + lane];
    double lg[8];
#pragma unroll
    for (int e = 0; e < 8; e++) {
        const float4* wv = (const float4*)(wr + (size_t)e * DIM);
        double s = 0.0;
#pragma unroll
        for (int q = 0; q < 4; q++) {
            float4 a = xv[q], b = wv[q * 64 + lane];
            s += (double)a.x * b.x + (double)a.y * b.y + (double)a.z * b.z + (double)a.w * b.w;
        }
#pragma unroll
        for (int d = 1; d < 64; d <<= 1) s += __shfl_xor(s, d);
        lg[e] = s;
    }
    double m = lg[0];
#pragma unroll
    for (int e = 1; e < 8; e++) m = lg[e] > m ? lg[e] : m;
    double ex[8], sum = 0.0;
#pragma unroll
    for (int e = 0; e < 8; e++) { ex[e] = exp(lg[e] - m); sum += ex[e]; }
    if (lane < 8) probs[(size_t)t * 8 + lane] = (float)(ex[lane] / sum);
    if (lane == 0) {
        int am = 0; double bv = lg[0];
#pragma unroll
        for (int e = 1; e < 8; e++) if (lg[e] > bv) { bv = lg[e]; am = e; }  // first-max = jnp.argmax
        eidx[t] = am;
        atomicAdd(&counts[am], 1);
    }
}

// ------------- scan: offsets (128-padded prefix), aux_loss (deterministic) ---
__global__ __launch_bounds__(256) void scan_aux_k(const float* __restrict__ probs,
                                                  const int* __restrict__ counts,
                                                  int* __restrict__ offsets,
                                                  float* __restrict__ auxout)
{
    __shared__ double red[256][8];
    int tid = threadIdx.x;
    double ps[8] = {0, 0, 0, 0, 0, 0, 0, 0};
    for (int t = tid; t < T_TOK; t += 256) {
#pragma unroll
        for (int e = 0; e < 8; e++) ps[e] += (double)probs[(size_t)t * 8 + e];
    }
#pragma unroll
    for (int e = 0; e < 8; e++) red[tid][e] = ps[e];
    __syncthreads();
    for (int s = 128; s > 0; s >>= 1) {
        if (tid < s) {
#pragma unroll
            for (int e = 0; e < 8; e++) red[tid][e] += red[tid + s][e];
        }
        __syncthreads();
    }
    if (tid == 0) {
        double aux = 0.0; int off = 0;
#pragma unroll
        for (int e = 0; e < 8; e++) {
            offsets[e] = off;
            off += (counts[e] + 127) & ~127;
            aux += ((double)counts[e] / T_TOK) * (red[0][e] / T_TOK);
        }
        auxout[0] = (float)(aux * NEXP);
    }
}

// ---------------- gather: slot assign + x -> bf16 gathered copy --------------
__global__ __launch_bounds__(256) void gather_k(const float* __restrict__ x,
                                                const int* __restrict__ eidx,
                                                const int* __restrict__ offsets,
                                                int* __restrict__ slotctr,
                                                int* __restrict__ tok,
                                                ushort* __restrict__ xg)
{
    int tid = threadIdx.x, w = tid >> 6, lane = tid & 63;
    int t = blockIdx.x * 4 + w;
    int slot = 0;
    if (lane == 0) {
        int e = eidx[t];
        slot = offsets[e] + atomicAdd(&slotctr[e], 1);
        tok[slot] = t;
    }
    slot = __shfl(slot, 0);
    const float4* xr = (const float4*)(x + (size_t)t * DIM);
    ushort4* xo = (ushort4*)(xg + (size_t)slot * DIM);
#pragma unroll
    for (int q = 0; q < 4; q++) {
        float4 v = xr[q * 64 + lane];
        ushort4 b;
        b.x = f2bf(v.x); b.y = f2bf(v.y); b.z = f2bf(v.z); b.w = f2bf(v.w);
        xo[q * 64 + lane] = b;
    }
}

// -------- materialize W_fc[e][j*1024+o][k*256+l] = sum_i A[i,j,k]*S[i,o,l] ---
__global__ __launch_bounds__(256) void wfc_k(const float* __restrict__ A,
                                             const float* __restrict__ S,
                                             ushort* __restrict__ W)
{
    int b = blockIdx.x;
    int e = b >> 10, o = b & 1023;
    int l = threadIdx.x;
    __shared__ float Ash[64];
    if (l < 64) Ash[l] = A[e * 64 + l];
    __syncthreads();
    float s0 = S[((size_t)(e * 4 + 0) * 1024 + o) * 256 + l];
    float s1 = S[((size_t)(e * 4 + 1) * 1024 + o) * 256 + l];
    float s2 = S[((size_t)(e * 4 + 2) * 1024 + o) * 256 + l];
    float s3 = S[((size_t)(e * 4 + 3) * 1024 + o) * 256 + l];
    size_t base = (size_t)e * 4194304ull;
#pragma unroll
    for (int j = 0; j < 4; j++)
#pragma unroll
        for (int k = 0; k < 4; k++) {
            float v = Ash[j * 4 + k] * s0 + Ash[16 + j * 4 + k] * s1 +
                      Ash[32 + j * 4 + k] * s2 + Ash[48 + j * 4 + k] * s3;
            W[base + (size_t)(j * 1024 + o) * 1024 + k * 256 + l] = f2bf(v);
        }
}

// ------- materialize W_proj[e][j*256+o][k*1024+l] = sum_i A[i,j,k]*S[i,o,l] --
__global__ __launch_bounds__(256) void wpj_k(const float* __restrict__ A,
                                             const float* __restrict__ S,
                                             ushort* __restrict__ W)
{
    int b = blockIdx.x;
    int e = b >> 8, o = b & 255;
    int tid = threadIdx.x;
    __shared__ float Ash[64];
    if (tid < 64) Ash[tid] = A[e * 64 + tid];
    __syncthreads();
    float s[4][4];
#pragma unroll
    for (int i = 0; i < 4; i++)
#pragma unroll
        for (int q = 0; q < 4; q++)
            s[i][q] = S[((size_t)(e * 4 + i) * 256 + o) * 1024 + q * 256 + tid];
    size_t base = (size_t)e * 4194304ull;
#pragma unroll
    for (int j = 0; j < 4; j++)
#pragma unroll
        for (int k = 0; k < 4; k++) {
            float a0 = Ash[j * 4 + k], a1 = Ash[16 + j * 4 + k];
            float a2 = Ash[32 + j * 4 + k], a3 = Ash[48 + j * 4 + k];
#pragma unroll
            for (int q = 0; q < 4; q++) {
                float v = a0 * s[0][q] + a1 * s[1][q] + a2 * s[2][q] + a3 * s[3][q];
                W[base + (size_t)(j * 256 + o) * 4096 + k * 1024 + q * 256 + tid] = f2bf(v);
            }
        }
}

// ---------------- MFMA GEMM: C[m,n] = sum_k A[m,k] * W[n,k]  (B^T layout) ----
// 128x128 tile, BK=64, 4 waves (2x2), each wave 4x4 frags of 16x16x32 bf16.
// FC: epilogue leaky(0.5)+square -> h bf16.  !FC: scatter rows to out f32.
template <int KDIM, int NDIM, bool FC>
__global__ __launch_bounds__(256) void moe_gemm_k(const ushort* __restrict__ Abuf,
                                                  const ushort* __restrict__ Wbuf,
                                                  ushort* __restrict__ Hout,
                                                  float* __restrict__ Yout,
                                                  const int* __restrict__ counts,
                                                  const int* __restrict__ offsets,
                                                  const int* __restrict__ tok)
{
    __shared__ __align__(16) ushort As[128 * 64];
    __shared__ __align__(16) ushort Bs[128 * 64];
    int e = -1, mt = 0, acct = 0;
    int ms = blockIdx.x;
#pragma unroll
    for (int i = 0; i < 8; i++) {
        int tiles = (counts[i] + 127) >> 7;
        if (e < 0 && ms < acct + tiles) { e = i; mt = ms - acct; }
        acct += tiles;
    }
    if (e < 0) return;
    int m_base = offsets[e] + mt * 128;
    int n_base = blockIdx.y * 128;
    int tid = threadIdx.x, w = tid >> 6, lane = tid & 63;
    int wm = w >> 1, wn = w & 1;
    const ushort* Ab = Abuf + (size_t)m_base * KDIM;
    const ushort* Bb = Wbuf + (size_t)e * NDIM * KDIM + (size_t)n_base * KDIM;
    int lr = lane >> 3, lc = (lane & 7) * 8;
    f32x4 acc[4][4];
#pragma unroll
    for (int i = 0; i < 4; i++)
#pragma unroll
        for (int j = 0; j < 4; j++) acc[i][j] = (f32x4){0.f, 0.f, 0.f, 0.f};

    for (int k0 = 0; k0 < KDIM; k0 += 64) {
#pragma unroll
        for (int i = 0; i < 4; i++) {
            int r0 = i * 32 + w * 8;   // 8 rows per wave-issue, linear LDS dest
            gload_lds16(Ab + (size_t)(r0 + lr) * KDIM + k0 + lc, As + r0 * 64);
            gload_lds16(Bb + (size_t)(r0 + lr) * KDIM + k0 + lc, Bs + r0 * 64);
        }
        __syncthreads();
#pragma unroll
        for (int ks = 0; ks < 2; ks++) {
            short8 a[4], b[4];
#pragma unroll
            for (int f = 0; f < 4; f++)
                a[f] = *(const short8*)&As[(wm * 64 + f * 16 + (lane & 15)) * 64 + ks * 32 + (lane >> 4) * 8];
#pragma unroll
            for (int f = 0; f < 4; f++)
                b[f] = *(const short8*)&Bs[(wn * 64 + f * 16 + (lane & 15)) * 64 + ks * 32 + (lane >> 4) * 8];
#pragma unroll
            for (int mf = 0; mf < 4; mf++)
#pragma unroll
                for (int nf = 0; nf < 4; nf++)
                    acc[mf][nf] = __builtin_amdgcn_mfma_f32_16x16x32_bf16(a[mf], b[nf], acc[mf][nf], 0, 0, 0);
        }
        __syncthreads();
    }

    int col0 = n_base + wn * 64;
    int row0 = wm * 64 + (lane >> 4) * 4;   // C/D: col=lane&15, row=(lane>>4)*4+reg
    if (FC) {
#pragma unroll
        for (int mf = 0; mf < 4; mf++)
#pragma unroll
            for (int nf = 0; nf < 4; nf++) {
                int col = col0 + nf * 16 + (lane & 15);
#pragma unroll
                for (int r = 0; r < 4; r++) {
                    float v = acc[mf][nf][r];
                    v = v >= 0.f ? v : 0.5f * v;   // leaky relu slope 0.5
                    v = v * v;                     // square
                    Hout[(size_t)(m_base + row0 + mf * 16 + r) * NDIM + col] = f2bf(v);
                }
            }
    } else {
        int limit = offsets[e] + counts[e];
#pragma unroll
        for (int mf = 0; mf < 4; mf++) {
            int tk[4]; bool vld[4];
#pragma unroll
            for (int r = 0; r < 4; r++) {
                int slot = m_base + row0 + mf * 16 + r;
                vld[r] = slot < limit;
                tk[r] = vld[r] ? tok[slot] : 0;
            }
#pragma unroll
            for (int nf = 0; nf < 4; nf++) {
                int col = col0 + nf * 16 + (lane & 15);
#pragma unroll
                for (int r = 0; r < 4; r++)
                    if (vld[r]) Yout[(size_t)tk[r] * NDIM + col] = acc[mf][nf][r];
            }
        }
    }
}

extern "C" void kernel_launch(void* const* d_in, const int* in_sizes, int n_in,
                              void* d_out, int out_size, void* d_ws, size_t ws_size,
                              hipStream_t stream)
{
    const float* x    = (const float*)d_in[0];
    const float* wr   = (const float*)d_in[1];
    const float* A_fc = (const float*)d_in[2];
    const float* S_fc = (const float*)d_in[3];
    const float* A_pj = (const float*)d_in[4];
    const float* S_pj = (const float*)d_in[5];
    float* out = (float*)d_out;
    char* ws = (char*)d_ws;

    ushort* Wfc   = (ushort*)(ws + OFF_WFC);
    ushort* Wpj   = (ushort*)(ws + OFF_WPROJ);
    ushort* xg    = (ushort*)(ws + OFF_XG);
    ushort* h     = (ushort*)(ws + OFF_H);
    float*  probs = (float*)(ws + OFF_PROBS);
    int*    eidx  = (int*)(ws + OFF_EIDX);
    int*    tok   = (int*)(ws + OFF_TOK);
    int*    counts  = (int*)(ws + OFF_CNT);
    int*    slotctr = counts + 8;
    int*    offsets = counts + 16;

    hipMemsetAsync(counts, 0, 64, stream);  // counts + slotctr
    router_k<<<T_TOK / 4, 256, 0, stream>>>(x, wr, probs, eidx, counts);
    scan_aux_k<<<1, 256, 0, stream>>>(probs, counts, offsets, out + (size_t)T_TOK * DIM);
    gather_k<<<T_TOK / 4, 256, 0, stream>>>(x, eidx, offsets, slotctr, tok, xg);
    wfc_k<<<NEXP * 1024, 256, 0, stream>>>(A_fc, S_fc, Wfc);
    wpj_k<<<NEXP * 256, 256, 0, stream>>>(A_pj, S_pj, Wpj);
    // max m-tiles across experts: 4096/128 + 8 partial = 40
    moe_gemm_k<1024, 4096, true><<<dim3(40, 32), 256, 0, stream>>>(xg, Wfc, h, nullptr, counts, offsets, tok);
    moe_gemm_k<4096, 1024, false><<<dim3(40, 8), 256, 0, stream>>>(h, Wpj, nullptr, out, counts, offsets, tok);
}

// Round 2
// 233.304 us; speedup vs baseline: 2.2153x; 2.2153x over previous
//
#include <hip/hip_runtime.h>
#include <hip/hip_bf16.h>

// MoE PHM MLP, MI355X. B=2,S=2048,D=1024 -> T=4096 tokens; E=8, N=4, HID=4096.
// Pipeline: router(f64 logits, no atomics) -> plan (single block: histogram,
// stable rank, offsets, aux) -> gather(bf16 copy) -> materialize
// W_eff = sum_i A_i (x) S_i in bf16 -> per-expert MFMA GEMM fc (+leaky^2) ->
// per-expert MFMA GEMM proj (+scatter to out).
//
// Workspace layout (~178.2 MiB):
//   [0,64MiB)          W_fc   bf16 [E][4096][1024]
//   [64,128MiB)        W_proj bf16 [E][1024][4096]
//   xg   bf16 [5120][1024]  (gathered tokens, 128-padded per expert)
//   h    bf16 [5120][4096]
//   probs f32 [T][8], eidx int[T], tok int[5120], counts/offsets int[8], slot int[T]

#define T_TOK 4096
#define DIM   1024
#define NEXP  8
#define HIDD  4096
#define SLOTS 5120

static constexpr size_t OFF_WFC   = 0;
static constexpr size_t OFF_WPROJ = 67108864ull;
static constexpr size_t OFF_XG    = 134217728ull;
static constexpr size_t OFF_H     = 144703488ull;
static constexpr size_t OFF_PROBS = 186646528ull;
static constexpr size_t OFF_EIDX  = OFF_PROBS + (size_t)T_TOK*8*4;
static constexpr size_t OFF_TOK   = OFF_EIDX + (size_t)T_TOK*4;
static constexpr size_t OFF_CNT   = OFF_TOK + (size_t)SLOTS*4;
static constexpr size_t OFF_SLOT  = OFF_CNT + 1024;

typedef __attribute__((ext_vector_type(8))) short short8;
typedef __attribute__((ext_vector_type(4))) float f32x4;

static __device__ __forceinline__ ushort f2bf(float f) {
    __hip_bfloat16 h = __float2bfloat16(f);
    return __builtin_bit_cast(ushort, h);
}

static __device__ __forceinline__ void gload_lds16(const ushort* g, ushort* l) {
    __builtin_amdgcn_global_load_lds((const __attribute__((address_space(1))) void*)g,
                                     (__attribute__((address_space(3))) void*)l,
                                     16, 0, 0);
}

// ---------------- router: f64 logits, softmax probs, argmax ------------------
__global__ __launch_bounds__(256) void router_k(const float* __restrict__ x,
                                                const float* __restrict__ wr,
                                                float* __restrict__ probs,
                                                int* __restrict__ eidx)
{
    int tid = threadIdx.x, w = tid >> 6, lane = tid & 63;
    int t = blockIdx.x * 4 + w;
    const float4* xr = (const float4*)(x + (size_t)t * DIM);
    float4 xv[4];
#pragma unroll
    for (int q = 0; q < 4; q++) xv[q] = xr[q * 64 + lane];
    double lg[8];
#pragma unroll
    for (int e = 0; e < 8; e++) {
        const float4* wv = (const float4*)(wr + (size_t)e * DIM);
        double s = 0.0;
#pragma unroll
        for (int q = 0; q < 4; q++) {
            float4 a = xv[q], b = wv[q * 64 + lane];
            s += (double)a.x * b.x + (double)a.y * b.y + (double)a.z * b.z + (double)a.w * b.w;
        }
#pragma unroll
        for (int d = 1; d < 64; d <<= 1) s += __shfl_xor(s, d);
        lg[e] = s;
    }
    double m = lg[0];
#pragma unroll
    for (int e = 1; e < 8; e++) m = lg[e] > m ? lg[e] : m;
    double ex[8], sum = 0.0;
#pragma unroll
    for (int e = 0; e < 8; e++) { ex[e] = exp(lg[e] - m); sum += ex[e]; }
    if (lane < 8) probs[(size_t)t * 8 + lane] = (float)(ex[lane] / sum);
    if (lane == 0) {
        int am = 0; double bv = lg[0];
#pragma unroll
        for (int e = 1; e < 8; e++) if (lg[e] > bv) { bv = lg[e]; am = e; }  // first-max = jnp.argmax
        eidx[t] = am;
    }
}

// --- plan: single block. histogram, stable counting-sort rank, offsets, aux --
__global__ __launch_bounds__(256) void plan_k(const float* __restrict__ probs,
                                              const int* __restrict__ eidx,
                                              int* __restrict__ counts,
                                              int* __restrict__ offsets,
                                              int* __restrict__ slot,
                                              int* __restrict__ tok,
                                              float* __restrict__ auxout)
{
    __shared__ int hist[256][8];     // 8 KB
    __shared__ double red[256][8];   // 16 KB
    __shared__ int offs[8];
    int tid = threadIdx.x;
    int base = tid * 16;
    int le[16];
    int lc[8] = {0,0,0,0,0,0,0,0};
#pragma unroll
    for (int j = 0; j < 16; j++) { le[j] = eidx[base + j]; lc[le[j]]++; }
#pragma unroll
    for (int e = 0; e < 8; e++) hist[tid][e] = lc[e];
    __syncthreads();
    // inclusive Hillis-Steele scan over tid for all 8 experts
    for (int s = 1; s < 256; s <<= 1) {
        int v[8];
        if (tid >= s) {
#pragma unroll
            for (int e = 0; e < 8; e++) v[e] = hist[tid - s][e];
        }
        __syncthreads();
        if (tid >= s) {
#pragma unroll
            for (int e = 0; e < 8; e++) hist[tid][e] += v[e];
        }
        __syncthreads();
    }
    int myBase[8];
#pragma unroll
    for (int e = 0; e < 8; e++) myBase[e] = hist[tid][e] - lc[e];  // exclusive
    if (tid == 0) {
        int off = 0;
#pragma unroll
        for (int e = 0; e < 8; e++) {
            int c = hist[255][e];
            counts[e] = c;
            offsets[e] = off; offs[e] = off;
            off += (c + 127) & ~127;
        }
    }
    __syncthreads();
    // stable slot assignment
    int cur[8];
#pragma unroll
    for (int e = 0; e < 8; e++) cur[e] = myBase[e];
#pragma unroll
    for (int j = 0; j < 16; j++) {
        int e = le[j];
        int s_ = offs[e] + cur[e]++;
        slot[base + j] = s_;
        tok[s_] = base + j;
    }
    // aux loss: sum_e (counts[e]/T) * mean_t(probs[t][e]) * E
    double ps[8] = {0, 0, 0, 0, 0, 0, 0, 0};
    for (int t = tid; t < T_TOK; t += 256) {
#pragma unroll
        for (int e = 0; e < 8; e++) ps[e] += (double)probs[(size_t)t * 8 + e];
    }
#pragma unroll
    for (int e = 0; e < 8; e++) red[tid][e] = ps[e];
    __syncthreads();
    for (int s = 128; s > 0; s >>= 1) {
        if (tid < s) {
#pragma unroll
            for (int e = 0; e < 8; e++) red[tid][e] += red[tid + s][e];
        }
        __syncthreads();
    }
    if (tid == 0) {
        double aux = 0.0;
#pragma unroll
        for (int e = 0; e < 8; e++)
            aux += ((double)hist[255][e] / T_TOK) * (red[0][e] / T_TOK);
        auxout[0] = (float)(aux * NEXP);
    }
}

// ---------------- gather: x -> bf16 at precomputed slot ----------------------
__global__ __launch_bounds__(256) void gather_k(const float* __restrict__ x,
                                                const int* __restrict__ slot,
                                                ushort* __restrict__ xg)
{
    int tid = threadIdx.x, w = tid >> 6, lane = tid & 63;
    int t = blockIdx.x * 4 + w;
    int s = slot[t];
    const float4* xr = (const float4*)(x + (size_t)t * DIM);
    ushort4* xo = (ushort4*)(xg + (size_t)s * DIM);
#pragma unroll
    for (int q = 0; q < 4; q++) {
        float4 v = xr[q * 64 + lane];
        ushort4 b;
        b.x = f2bf(v.x); b.y = f2bf(v.y); b.z = f2bf(v.z); b.w = f2bf(v.w);
        xo[q * 64 + lane] = b;
    }
}

// -------- materialize W_fc[e][j*1024+o][k*256+l] = sum_i A[i,j,k]*S[i,o,l] ---
__global__ __launch_bounds__(256) void wfc_k(const float* __restrict__ A,
                                             const float* __restrict__ S,
                                             ushort* __restrict__ W)
{
    int b = blockIdx.x;
    int e = b >> 10, o = b & 1023;
    int l = threadIdx.x;
    __shared__ float Ash[64];
    if (l < 64) Ash[l] = A[e * 64 + l];
    __syncthreads();
    float s0 = S[((size_t)(e * 4 + 0) * 1024 + o) * 256 + l];
    float s1 = S[((size_t)(e * 4 + 1) * 1024 + o) * 256 + l];
    float s2 = S[((size_t)(e * 4 + 2) * 1024 + o) * 256 + l];
    float s3 = S[((size_t)(e * 4 + 3) * 1024 + o) * 256 + l];
    size_t base = (size_t)e * 4194304ull;
#pragma unroll
    for (int j = 0; j < 4; j++)
#pragma unroll
        for (int k = 0; k < 4; k++) {
            float v = Ash[j * 4 + k] * s0 + Ash[16 + j * 4 + k] * s1 +
                      Ash[32 + j * 4 + k] * s2 + Ash[48 + j * 4 + k] * s3;
            W[base + (size_t)(j * 1024 + o) * 1024 + k * 256 + l] = f2bf(v);
        }
}

// ------- materialize W_proj[e][j*256+o][k*1024+l] = sum_i A[i,j,k]*S[i,o,l] --
__global__ __launch_bounds__(256) void wpj_k(const float* __restrict__ A,
                                             const float* __restrict__ S,
                                             ushort* __restrict__ W)
{
    int b = blockIdx.x;
    int e = b >> 8, o = b & 255;
    int tid = threadIdx.x;
    __shared__ float Ash[64];
    if (tid < 64) Ash[tid] = A[e * 64 + tid];
    __syncthreads();
    float s[4][4];
#pragma unroll
    for (int i = 0; i < 4; i++)
#pragma unroll
        for (int q = 0; q < 4; q++)
            s[i][q] = S[((size_t)(e * 4 + i) * 256 + o) * 1024 + q * 256 + tid];
    size_t base = (size_t)e * 4194304ull;
#pragma unroll
    for (int j = 0; j < 4; j++)
#pragma unroll
        for (int k = 0; k < 4; k++) {
            float a0 = Ash[j * 4 + k], a1 = Ash[16 + j * 4 + k];
            float a2 = Ash[32 + j * 4 + k], a3 = Ash[48 + j * 4 + k];
#pragma unroll
            for (int q = 0; q < 4; q++) {
                float v = a0 * s[0][q] + a1 * s[1][q] + a2 * s[2][q] + a3 * s[3][q];
                W[base + (size_t)(j * 256 + o) * 4096 + k * 1024 + q * 256 + tid] = f2bf(v);
            }
        }
}

// ---------------- MFMA GEMM: C[m,n] = sum_k A[m,k] * W[n,k]  (B^T layout) ----
// 128x128 tile, BK=64, 4 waves (2x2), each wave 4x4 frags of 16x16x32 bf16.
// FC: epilogue leaky(0.5)+square -> h bf16.  !FC: scatter rows to out f32.
template <int KDIM, int NDIM, bool FC>
__global__ __launch_bounds__(256) void moe_gemm_k(const ushort* __restrict__ Abuf,
                                                  const ushort* __restrict__ Wbuf,
                                                  ushort* __restrict__ Hout,
                                                  float* __restrict__ Yout,
                                                  const int* __restrict__ counts,
                                                  const int* __restrict__ offsets,
                                                  const int* __restrict__ tok)
{
    __shared__ __align__(16) ushort As[128 * 64];
    __shared__ __align__(16) ushort Bs[128 * 64];
    int e = -1, mt = 0, acct = 0;
    int ms = blockIdx.x;
#pragma unroll
    for (int i = 0; i < 8; i++) {
        int tiles = (counts[i] + 127) >> 7;
        if (e < 0 && ms < acct + tiles) { e = i; mt = ms - acct; }
        acct += tiles;
    }
    if (e < 0) return;
    int m_base = offsets[e] + mt * 128;
    int n_base = blockIdx.y * 128;
    int tid = threadIdx.x, w = tid >> 6, lane = tid & 63;
    int wm = w >> 1, wn = w & 1;
    const ushort* Ab = Abuf + (size_t)m_base * KDIM;
    const ushort* Bb = Wbuf + (size_t)e * NDIM * KDIM + (size_t)n_base * KDIM;
    int lr = lane >> 3, lc = (lane & 7) * 8;
    f32x4 acc[4][4];
#pragma unroll
    for (int i = 0; i < 4; i++)
#pragma unroll
        for (int j = 0; j < 4; j++) acc[i][j] = (f32x4){0.f, 0.f, 0.f, 0.f};

    for (int k0 = 0; k0 < KDIM; k0 += 64) {
#pragma unroll
        for (int i = 0; i < 4; i++) {
            int r0 = i * 32 + w * 8;   // 8 rows per wave-issue, linear LDS dest
            gload_lds16(Ab + (size_t)(r0 + lr) * KDIM + k0 + lc, As + r0 * 64);
            gload_lds16(Bb + (size_t)(r0 + lr) * KDIM + k0 + lc, Bs + r0 * 64);
        }
        __syncthreads();
#pragma unroll
        for (int ks = 0; ks < 2; ks++) {
            short8 a[4], b[4];
#pragma unroll
            for (int f = 0; f < 4; f++)
                a[f] = *(const short8*)&As[(wm * 64 + f * 16 + (lane & 15)) * 64 + ks * 32 + (lane >> 4) * 8];
#pragma unroll
            for (int f = 0; f < 4; f++)
                b[f] = *(const short8*)&Bs[(wn * 64 + f * 16 + (lane & 15)) * 64 + ks * 32 + (lane >> 4) * 8];
#pragma unroll
            for (int mf = 0; mf < 4; mf++)
#pragma unroll
                for (int nf = 0; nf < 4; nf++)
                    acc[mf][nf] = __builtin_amdgcn_mfma_f32_16x16x32_bf16(a[mf], b[nf], acc[mf][nf], 0, 0, 0);
        }
        __syncthreads();
    }

    int col0 = n_base + wn * 64;
    int row0 = wm * 64 + (lane >> 4) * 4;   // C/D: col=lane&15, row=(lane>>4)*4+reg
    if (FC) {
#pragma unroll
        for (int mf = 0; mf < 4; mf++)
#pragma unroll
            for (int nf = 0; nf < 4; nf++) {
                int col = col0 + nf * 16 + (lane & 15);
#pragma unroll
                for (int r = 0; r < 4; r++) {
                    float v = acc[mf][nf][r];
                    v = v >= 0.f ? v : 0.5f * v;   // leaky relu slope 0.5
                    v = v * v;                     // square
                    Hout[(size_t)(m_base + row0 + mf * 16 + r) * NDIM + col] = f2bf(v);
                }
            }
    } else {
        int limit = offsets[e] + counts[e];
#pragma unroll
        for (int mf = 0; mf < 4; mf++) {
            int tk[4]; bool vld[4];
#pragma unroll
            for (int r = 0; r < 4; r++) {
                int slot = m_base + row0 + mf * 16 + r;
                vld[r] = slot < limit;
                tk[r] = vld[r] ? tok[slot] : 0;
            }
#pragma unroll
            for (int nf = 0; nf < 4; nf++) {
                int col = col0 + nf * 16 + (lane & 15);
#pragma unroll
                for (int r = 0; r < 4; r++)
                    if (vld[r]) Yout[(size_t)tk[r] * NDIM + col] = acc[mf][nf][r];
            }
        }
    }
}

extern "C" void kernel_launch(void* const* d_in, const int* in_sizes, int n_in,
                              void* d_out, int out_size, void* d_ws, size_t ws_size,
                              hipStream_t stream)
{
    const float* x    = (const float*)d_in[0];
    const float* wr   = (const float*)d_in[1];
    const float* A_fc = (const float*)d_in[2];
    const float* S_fc = (const float*)d_in[3];
    const float* A_pj = (const float*)d_in[4];
    const float* S_pj = (const float*)d_in[5];
    float* out = (float*)d_out;
    char* ws = (char*)d_ws;

    ushort* Wfc   = (ushort*)(ws + OFF_WFC);
    ushort* Wpj   = (ushort*)(ws + OFF_WPROJ);
    ushort* xg    = (ushort*)(ws + OFF_XG);
    ushort* h     = (ushort*)(ws + OFF_H);
    float*  probs = (float*)(ws + OFF_PROBS);
    int*    eidx  = (int*)(ws + OFF_EIDX);
    int*    tok   = (int*)(ws + OFF_TOK);
    int*    counts  = (int*)(ws + OFF_CNT);
    int*    offsets = counts + 16;
    int*    slot  = (int*)(ws + OFF_SLOT);

    router_k<<<T_TOK / 4, 256, 0, stream>>>(x, wr, probs, eidx);
    plan_k<<<1, 256, 0, stream>>>(probs, eidx, counts, offsets, slot, tok,
                                  out + (size_t)T_TOK * DIM);
    gather_k<<<T_TOK / 4, 256, 0, stream>>>(x, slot, xg);
    wfc_k<<<NEXP * 1024, 256, 0, stream>>>(A_fc, S_fc, Wfc);
    wpj_k<<<NEXP * 256, 256, 0, stream>>>(A_pj, S_pj, Wpj);
    // max m-tiles across experts: 4096/128 + 8 partial = 40
    moe_gemm_k<1024, 4096, true><<<dim3(40, 32), 256, 0, stream>>>(xg, Wfc, h, nullptr, counts, offsets, tok);
    moe_gemm_k<4096, 1024, false><<<dim3(40, 8), 256, 0, stream>>>(h, Wpj, nullptr, out, counts, offsets, tok);
}

// Round 3
// 205.524 us; speedup vs baseline: 2.5148x; 1.1352x over previous
//
#include <hip/hip_runtime.h>
#include <hip/hip_bf16.h>

// MoE PHM MLP, MI355X. B=2,S=2048,D=1024 -> T=4096 tokens; E=8, N=4, HID=4096.
// Pipeline: router(f64 logits, no atomics) -> plan (single block) -> gather ->
// materialize W_eff = sum_i A_i (x) S_i (bf16) -> MFMA GEMM fc (+leaky^2) ->
// MFMA GEMM proj (+scatter). GEMMs: 128x128x64 tiles, double-buffered
// global_load_lds prefetch (2-phase), XOR-swizzled LDS (swizzle applied on the
// GLOBAL source so the linear gload_lds dest + swizzled ds_read agree),
// XCD-grouped block decode (b&7 owns fixed N-panels for L2 reuse).

#define T_TOK 4096
#define DIM   1024
#define NEXP  8
#define HIDD  4096
#define SLOTS 5120

static constexpr size_t OFF_WFC   = 0;
static constexpr size_t OFF_WPROJ = 67108864ull;
static constexpr size_t OFF_XG    = 134217728ull;
static constexpr size_t OFF_H     = 144703488ull;
static constexpr size_t OFF_PROBS = 186646528ull;
static constexpr size_t OFF_EIDX  = OFF_PROBS + (size_t)T_TOK*8*4;
static constexpr size_t OFF_TOK   = OFF_EIDX + (size_t)T_TOK*4;
static constexpr size_t OFF_CNT   = OFF_TOK + (size_t)SLOTS*4;
static constexpr size_t OFF_SLOT  = OFF_CNT + 1024;

typedef __attribute__((ext_vector_type(8))) short short8;
typedef __attribute__((ext_vector_type(4))) float f32x4;

static __device__ __forceinline__ ushort f2bf(float f) {
    __hip_bfloat16 h = __float2bfloat16(f);
    return __builtin_bit_cast(ushort, h);
}

static __device__ __forceinline__ void gload_lds16(const ushort* g, ushort* l) {
    __builtin_amdgcn_global_load_lds((const __attribute__((address_space(1))) void*)g,
                                     (__attribute__((address_space(3))) void*)l,
                                     16, 0, 0);
}

// ---------------- router: f64 logits, softmax probs, argmax ------------------
__global__ __launch_bounds__(256) void router_k(const float* __restrict__ x,
                                                const float* __restrict__ wr,
                                                float* __restrict__ probs,
                                                int* __restrict__ eidx)
{
    int tid = threadIdx.x, w = tid >> 6, lane = tid & 63;
    int t = blockIdx.x * 4 + w;
    const float4* xr = (const float4*)(x + (size_t)t * DIM);
    float4 xv[4];
#pragma unroll
    for (int q = 0; q < 4; q++) xv[q] = xr[q * 64 + lane];
    double lg[8];
#pragma unroll
    for (int e = 0; e < 8; e++) {
        const float4* wv = (const float4*)(wr + (size_t)e * DIM);
        double s = 0.0;
#pragma unroll
        for (int q = 0; q < 4; q++) {
            float4 a = xv[q], b = wv[q * 64 + lane];
            s += (double)a.x * b.x + (double)a.y * b.y + (double)a.z * b.z + (double)a.w * b.w;
        }
#pragma unroll
        for (int d = 1; d < 64; d <<= 1) s += __shfl_xor(s, d);
        lg[e] = s;
    }
    double m = lg[0];
#pragma unroll
    for (int e = 1; e < 8; e++) m = lg[e] > m ? lg[e] : m;
    double ex[8], sum = 0.0;
#pragma unroll
    for (int e = 0; e < 8; e++) { ex[e] = exp(lg[e] - m); sum += ex[e]; }
    if (lane < 8) probs[(size_t)t * 8 + lane] = (float)(ex[lane] / sum);
    if (lane == 0) {
        int am = 0; double bv = lg[0];
#pragma unroll
        for (int e = 1; e < 8; e++) if (lg[e] > bv) { bv = lg[e]; am = e; }  // first-max = jnp.argmax
        eidx[t] = am;
    }
}

// --- plan: single block. histogram, stable counting-sort rank, offsets, aux --
__global__ __launch_bounds__(256) void plan_k(const float* __restrict__ probs,
                                              const int* __restrict__ eidx,
                                              int* __restrict__ counts,
                                              int* __restrict__ offsets,
                                              int* __restrict__ slot,
                                              int* __restrict__ tok,
                                              float* __restrict__ auxout)
{
    __shared__ int hist[256][8];
    __shared__ double red[256][8];
    __shared__ int offs[8];
    int tid = threadIdx.x;
    int base = tid * 16;
    int le[16];
    int lc[8] = {0,0,0,0,0,0,0,0};
#pragma unroll
    for (int j = 0; j < 16; j++) { le[j] = eidx[base + j]; lc[le[j]]++; }
#pragma unroll
    for (int e = 0; e < 8; e++) hist[tid][e] = lc[e];
    __syncthreads();
    for (int s = 1; s < 256; s <<= 1) {
        int v[8];
        if (tid >= s) {
#pragma unroll
            for (int e = 0; e < 8; e++) v[e] = hist[tid - s][e];
        }
        __syncthreads();
        if (tid >= s) {
#pragma unroll
            for (int e = 0; e < 8; e++) hist[tid][e] += v[e];
        }
        __syncthreads();
    }
    int myBase[8];
#pragma unroll
    for (int e = 0; e < 8; e++) myBase[e] = hist[tid][e] - lc[e];
    if (tid == 0) {
        int off = 0;
#pragma unroll
        for (int e = 0; e < 8; e++) {
            int c = hist[255][e];
            counts[e] = c;
            offsets[e] = off; offs[e] = off;
            off += (c + 127) & ~127;
        }
    }
    __syncthreads();
    int cur[8];
#pragma unroll
    for (int e = 0; e < 8; e++) cur[e] = myBase[e];
#pragma unroll
    for (int j = 0; j < 16; j++) {
        int e = le[j];
        int s_ = offs[e] + cur[e]++;
        slot[base + j] = s_;
        tok[s_] = base + j;
    }
    double ps[8] = {0, 0, 0, 0, 0, 0, 0, 0};
    for (int t = tid; t < T_TOK; t += 256) {
#pragma unroll
        for (int e = 0; e < 8; e++) ps[e] += (double)probs[(size_t)t * 8 + e];
    }
#pragma unroll
    for (int e = 0; e < 8; e++) red[tid][e] = ps[e];
    __syncthreads();
    for (int s = 128; s > 0; s >>= 1) {
        if (tid < s) {
#pragma unroll
            for (int e = 0; e < 8; e++) red[tid][e] += red[tid + s][e];
        }
        __syncthreads();
    }
    if (tid == 0) {
        double aux = 0.0;
#pragma unroll
        for (int e = 0; e < 8; e++)
            aux += ((double)hist[255][e] / T_TOK) * (red[0][e] / T_TOK);
        auxout[0] = (float)(aux * NEXP);
    }
}

// ---------------- gather: x -> bf16 at precomputed slot ----------------------
__global__ __launch_bounds__(256) void gather_k(const float* __restrict__ x,
                                                const int* __restrict__ slot,
                                                ushort* __restrict__ xg)
{
    int tid = threadIdx.x, w = tid >> 6, lane = tid & 63;
    int t = blockIdx.x * 4 + w;
    int s = slot[t];
    const float4* xr = (const float4*)(x + (size_t)t * DIM);
    ushort4* xo = (ushort4*)(xg + (size_t)s * DIM);
#pragma unroll
    for (int q = 0; q < 4; q++) {
        float4 v = xr[q * 64 + lane];
        ushort4 b;
        b.x = f2bf(v.x); b.y = f2bf(v.y); b.z = f2bf(v.z); b.w = f2bf(v.w);
        xo[q * 64 + lane] = b;
    }
}

// -------- materialize W_fc[e][j*1024+o][k*256+l] = sum_i A[i,j,k]*S[i,o,l] ---
__global__ __launch_bounds__(256) void wfc_k(const float* __restrict__ A,
                                             const float* __restrict__ S,
                                             ushort* __restrict__ W)
{
    int b = blockIdx.x;
    int e = b >> 10, o = b & 1023;
    int l = threadIdx.x;
    __shared__ float Ash[64];
    if (l < 64) Ash[l] = A[e * 64 + l];
    __syncthreads();
    float s0 = S[((size_t)(e * 4 + 0) * 1024 + o) * 256 + l];
    float s1 = S[((size_t)(e * 4 + 1) * 1024 + o) * 256 + l];
    float s2 = S[((size_t)(e * 4 + 2) * 1024 + o) * 256 + l];
    float s3 = S[((size_t)(e * 4 + 3) * 1024 + o) * 256 + l];
    size_t base = (size_t)e * 4194304ull;
#pragma unroll
    for (int j = 0; j < 4; j++)
#pragma unroll
        for (int k = 0; k < 4; k++) {
            float v = Ash[j * 4 + k] * s0 + Ash[16 + j * 4 + k] * s1 +
                      Ash[32 + j * 4 + k] * s2 + Ash[48 + j * 4 + k] * s3;
            W[base + (size_t)(j * 1024 + o) * 1024 + k * 256 + l] = f2bf(v);
        }
}

// ------- materialize W_proj[e][j*256+o][k*1024+l] = sum_i A[i,j,k]*S[i,o,l] --
__global__ __launch_bounds__(256) void wpj_k(const float* __restrict__ A,
                                             const float* __restrict__ S,
                                             ushort* __restrict__ W)
{
    int b = blockIdx.x;
    int e = b >> 8, o = b & 255;
    int tid = threadIdx.x;
    __shared__ float Ash[64];
    if (tid < 64) Ash[tid] = A[e * 64 + tid];
    __syncthreads();
    float s[4][4];
#pragma unroll
    for (int i = 0; i < 4; i++)
#pragma unroll
        for (int q = 0; q < 4; q++)
            s[i][q] = S[((size_t)(e * 4 + i) * 256 + o) * 1024 + q * 256 + tid];
    size_t base = (size_t)e * 4194304ull;
#pragma unroll
    for (int j = 0; j < 4; j++)
#pragma unroll
        for (int k = 0; k < 4; k++) {
            float a0 = Ash[j * 4 + k], a1 = Ash[16 + j * 4 + k];
            float a2 = Ash[32 + j * 4 + k], a3 = Ash[48 + j * 4 + k];
#pragma unroll
            for (int q = 0; q < 4; q++) {
                float v = a0 * s[0][q] + a1 * s[1][q] + a2 * s[2][q] + a3 * s[3][q];
                W[base + (size_t)(j * 256 + o) * 4096 + k * 1024 + q * 256 + tid] = f2bf(v);
            }
        }
}

// ---------------- MFMA GEMM: C[m,n] = sum_k A[m,k] * W[n,k]  (B^T layout) ----
// 128x128 tile, BK=64, 4 waves (2x2), 2-phase dbuf prefetch, XOR-swizzled LDS.
// LDS layout: tile[row][chunk] holds global[row][chunk ^ (row&7)] (chunk = 8
// ushorts = 16B). gload_lds dest stays linear; the source col is pre-swizzled.
// Grid is 1D; b&7 = XCD (round-robin dispatch), each XCD owns NBY/8 N-panels.
template <int KDIM, int NDIM, bool FC>
__global__ __launch_bounds__(256) void moe_gemm_k(const ushort* __restrict__ Abuf,
                                                  const ushort* __restrict__ Wbuf,
                                                  ushort* __restrict__ Hout,
                                                  float* __restrict__ Yout,
                                                  const int* __restrict__ counts,
                                                  const int* __restrict__ offsets,
                                                  const int* __restrict__ tok)
{
    __shared__ __align__(16) ushort As[2][128 * 64];
    __shared__ __align__(16) ushort Bs[2][128 * 64];
    constexpr int NBY = NDIM / 128;   // 32 (fc) or 8 (proj)
    constexpr int YPX = NBY / 8;      // N-panels per XCD
    int b = blockIdx.x;
    int nb = (b & 7) * YPX + (b >> 3) / 40;   // N-panel, fixed per XCD
    int ms = (b >> 3) % 40;                   // global m-tile
    int e = -1, mt = 0, acct = 0;
#pragma unroll
    for (int i = 0; i < 8; i++) {
        int tiles = (counts[i] + 127) >> 7;
        if (e < 0 && ms < acct + tiles) { e = i; mt = ms - acct; }
        acct += tiles;
    }
    if (e < 0) return;
    int m_base = offsets[e] + mt * 128;
    int n_base = nb * 128;
    int tid = threadIdx.x, w = tid >> 6, lane = tid & 63;
    int wm = w >> 1, wn = w & 1;
    const ushort* Ab = Abuf + (size_t)m_base * KDIM;
    const ushort* Bb = Wbuf + (size_t)e * NDIM * KDIM + (size_t)n_base * KDIM;
    int lr = lane >> 3;                        // staging row within 8-row group
    int lcs = (((lane & 7) ^ lr) << 3);        // swizzled source chunk (ushorts)
    f32x4 acc[4][4];
#pragma unroll
    for (int i = 0; i < 4; i++)
#pragma unroll
        for (int j = 0; j < 4; j++) acc[i][j] = (f32x4){0.f, 0.f, 0.f, 0.f};

    constexpr int NT = KDIM / 64;
    // prologue: stage tile 0 into buf 0
#pragma unroll
    for (int i = 0; i < 4; i++) {
        int r0 = i * 32 + w * 8;
        gload_lds16(Ab + (size_t)(r0 + lr) * KDIM + lcs, &As[0][r0 * 64]);
        gload_lds16(Bb + (size_t)(r0 + lr) * KDIM + lcs, &Bs[0][r0 * 64]);
    }
    __syncthreads();

    int cur = 0;
    for (int t = 0; t < NT; t++) {
        // 1) ds_read all fragments of buf[cur] (issued before gloads so the
        //    legalizer has no reason to guard them with a vmcnt wait)
        short8 af[2][4], bf[2][4];
#pragma unroll
        for (int ks = 0; ks < 2; ks++) {
#pragma unroll
            for (int f = 0; f < 4; f++) {
                int ra = wm * 64 + f * 16 + (lane & 15);
                int ca = (((ks * 4 + (lane >> 4)) ^ (lane & 7)) << 3);
                af[ks][f] = *(const short8*)&As[cur][ra * 64 + ca];
                int rb = wn * 64 + f * 16 + (lane & 15);
                bf[ks][f] = *(const short8*)&Bs[cur][rb * 64 + ca];
            }
        }
        // 2) prefetch tile t+1 into buf[cur^1]
        if (t + 1 < NT) {
            int k0 = (t + 1) * 64;
            int nx = cur ^ 1;
#pragma unroll
            for (int i = 0; i < 4; i++) {
                int r0 = i * 32 + w * 8;
                gload_lds16(Ab + (size_t)(r0 + lr) * KDIM + k0 + lcs, &As[nx][r0 * 64]);
                gload_lds16(Bb + (size_t)(r0 + lr) * KDIM + k0 + lcs, &Bs[nx][r0 * 64]);
            }
        }
        // 3) MFMA (hides the prefetch latency)
#pragma unroll
        for (int ks = 0; ks < 2; ks++)
#pragma unroll
            for (int mf = 0; mf < 4; mf++)
#pragma unroll
                for (int nf = 0; nf < 4; nf++)
                    acc[mf][nf] = __builtin_amdgcn_mfma_f32_16x16x32_bf16(af[ks][mf], bf[ks][nf], acc[mf][nf], 0, 0, 0);
        // 4) drain (vmcnt(0) lgkmcnt(0)) + barrier: publish buf[cur^1]
        __syncthreads();
        cur ^= 1;
    }

    int col0 = n_base + wn * 64;
    int row0 = wm * 64 + (lane >> 4) * 4;   // C/D: col=lane&15, row=(lane>>4)*4+reg
    if (FC) {
#pragma unroll
        for (int mf = 0; mf < 4; mf++)
#pragma unroll
            for (int nf = 0; nf < 4; nf++) {
                int col = col0 + nf * 16 + (lane & 15);
#pragma unroll
                for (int r = 0; r < 4; r++) {
                    float v = acc[mf][nf][r];
                    v = v >= 0.f ? v : 0.5f * v;   // leaky relu slope 0.5
                    v = v * v;                     // square
                    Hout[(size_t)(m_base + row0 + mf * 16 + r) * NDIM + col] = f2bf(v);
                }
            }
    } else {
        int limit = offsets[e] + counts[e];
#pragma unroll
        for (int mf = 0; mf < 4; mf++) {
            int tk[4]; bool vld[4];
#pragma unroll
            for (int r = 0; r < 4; r++) {
                int slot = m_base + row0 + mf * 16 + r;
                vld[r] = slot < limit;
                tk[r] = vld[r] ? tok[slot] : 0;
            }
#pragma unroll
            for (int nf = 0; nf < 4; nf++) {
                int col = col0 + nf * 16 + (lane & 15);
#pragma unroll
                for (int r = 0; r < 4; r++)
                    if (vld[r]) Yout[(size_t)tk[r] * NDIM + col] = acc[mf][nf][r];
            }
        }
    }
}

extern "C" void kernel_launch(void* const* d_in, const int* in_sizes, int n_in,
                              void* d_out, int out_size, void* d_ws, size_t ws_size,
                              hipStream_t stream)
{
    const float* x    = (const float*)d_in[0];
    const float* wr   = (const float*)d_in[1];
    const float* A_fc = (const float*)d_in[2];
    const float* S_fc = (const float*)d_in[3];
    const float* A_pj = (const float*)d_in[4];
    const float* S_pj = (const float*)d_in[5];
    float* out = (float*)d_out;
    char* ws = (char*)d_ws;

    ushort* Wfc   = (ushort*)(ws + OFF_WFC);
    ushort* Wpj   = (ushort*)(ws + OFF_WPROJ);
    ushort* xg    = (ushort*)(ws + OFF_XG);
    ushort* h     = (ushort*)(ws + OFF_H);
    float*  probs = (float*)(ws + OFF_PROBS);
    int*    eidx  = (int*)(ws + OFF_EIDX);
    int*    tok   = (int*)(ws + OFF_TOK);
    int*    counts  = (int*)(ws + OFF_CNT);
    int*    offsets = counts + 16;
    int*    slot  = (int*)(ws + OFF_SLOT);

    router_k<<<T_TOK / 4, 256, 0, stream>>>(x, wr, probs, eidx);
    plan_k<<<1, 256, 0, stream>>>(probs, eidx, counts, offsets, slot, tok,
                                  out + (size_t)T_TOK * DIM);
    gather_k<<<T_TOK / 4, 256, 0, stream>>>(x, slot, xg);
    wfc_k<<<NEXP * 1024, 256, 0, stream>>>(A_fc, S_fc, Wfc);
    wpj_k<<<NEXP * 256, 256, 0, stream>>>(A_pj, S_pj, Wpj);
    // 1D grids: 40 m-tiles x (NDIM/128) n-panels, XCD-grouped decode inside
    moe_gemm_k<1024, 4096, true><<<40 * 32, 256, 0, stream>>>(xg, Wfc, h, nullptr, counts, offsets, tok);
    moe_gemm_k<4096, 1024, false><<<40 * 8, 256, 0, stream>>>(h, Wpj, nullptr, out, counts, offsets, tok);
}

// Round 4
// 204.843 us; speedup vs baseline: 2.5231x; 1.0033x over previous
//
#include <hip/hip_runtime.h>
#include <hip/hip_bf16.h>

// MoE PHM MLP, MI355X. B=2,S=2048,D=1024 -> T=4096 tokens; E=8, N=4, HID=4096.
// router(f64) -> plan -> gather -> W_eff materialization (bf16) ->
// fc GEMM (m97 single-buffer structure + swizzle, epilogue leaky^2) ->
// proj GEMM (same structure, split-K=2 -> f32 partials) -> reduce+scatter.
//
// Workspace (~187 MiB):
//   [0,64MiB)    W_fc bf16 [E][4096][1024]; after fc GEMM this region is DEAD
//                and is reused for proj partials P[2][5120][1024] f32 (42 MiB).
//   [64,128MiB)  W_proj bf16 [E][1024][4096]
//   xg bf16 [5120][1024], h bf16 [5120][4096], probs f32, eidx, tok, counts, slot

#define T_TOK 4096
#define DIM   1024
#define NEXP  8
#define HIDD  4096
#define SLOTS 5120

static constexpr size_t OFF_WFC   = 0;
static constexpr size_t OFF_WPROJ = 67108864ull;
static constexpr size_t OFF_XG    = 134217728ull;
static constexpr size_t OFF_H     = 144703488ull;
static constexpr size_t OFF_PROBS = 186646528ull;
static constexpr size_t OFF_EIDX  = OFF_PROBS + (size_t)T_TOK*8*4;
static constexpr size_t OFF_TOK   = OFF_EIDX + (size_t)T_TOK*4;
static constexpr size_t OFF_CNT   = OFF_TOK + (size_t)SLOTS*4;
static constexpr size_t OFF_SLOT  = OFF_CNT + 1024;

typedef __attribute__((ext_vector_type(8))) short short8;
typedef __attribute__((ext_vector_type(4))) float f32x4;

static __device__ __forceinline__ ushort f2bf(float f) {
    __hip_bfloat16 h = __float2bfloat16(f);
    return __builtin_bit_cast(ushort, h);
}

static __device__ __forceinline__ void gload_lds16(const ushort* g, ushort* l) {
    __builtin_amdgcn_global_load_lds((const __attribute__((address_space(1))) void*)g,
                                     (__attribute__((address_space(3))) void*)l,
                                     16, 0, 0);
}

// ---------------- router: f64 logits, softmax probs, argmax ------------------
__global__ __launch_bounds__(256) void router_k(const float* __restrict__ x,
                                                const float* __restrict__ wr,
                                                float* __restrict__ probs,
                                                int* __restrict__ eidx)
{
    int tid = threadIdx.x, w = tid >> 6, lane = tid & 63;
    int t = blockIdx.x * 4 + w;
    const float4* xr = (const float4*)(x + (size_t)t * DIM);
    float4 xv[4];
#pragma unroll
    for (int q = 0; q < 4; q++) xv[q] = xr[q * 64 + lane];
    double lg[8];
#pragma unroll
    for (int e = 0; e < 8; e++) {
        const float4* wv = (const float4*)(wr + (size_t)e * DIM);
        double s = 0.0;
#pragma unroll
        for (int q = 0; q < 4; q++) {
            float4 a = xv[q], b = wv[q * 64 + lane];
            s += (double)a.x * b.x + (double)a.y * b.y + (double)a.z * b.z + (double)a.w * b.w;
        }
#pragma unroll
        for (int d = 1; d < 64; d <<= 1) s += __shfl_xor(s, d);
        lg[e] = s;
    }
    double m = lg[0];
#pragma unroll
    for (int e = 1; e < 8; e++) m = lg[e] > m ? lg[e] : m;
    double ex[8], sum = 0.0;
#pragma unroll
    for (int e = 0; e < 8; e++) { ex[e] = exp(lg[e] - m); sum += ex[e]; }
    if (lane < 8) probs[(size_t)t * 8 + lane] = (float)(ex[lane] / sum);
    if (lane == 0) {
        int am = 0; double bv = lg[0];
#pragma unroll
        for (int e = 1; e < 8; e++) if (lg[e] > bv) { bv = lg[e]; am = e; }  // first-max = jnp.argmax
        eidx[t] = am;
    }
}

// --- plan: single block. tok=-1 init, histogram, stable rank, offsets, aux ---
__global__ __launch_bounds__(256) void plan_k(const float* __restrict__ probs,
                                              const int* __restrict__ eidx,
                                              int* __restrict__ counts,
                                              int* __restrict__ offsets,
                                              int* __restrict__ slot,
                                              int* __restrict__ tok,
                                              float* __restrict__ auxout)
{
    __shared__ int hist[256][8];
    __shared__ double red[256][8];
    __shared__ int offs[8];
    int tid = threadIdx.x;
    for (int i = tid; i < SLOTS; i += 256) tok[i] = -1;
    int base = tid * 16;
    int le[16];
    int lc[8] = {0,0,0,0,0,0,0,0};
#pragma unroll
    for (int j = 0; j < 16; j++) { le[j] = eidx[base + j]; lc[le[j]]++; }
#pragma unroll
    for (int e = 0; e < 8; e++) hist[tid][e] = lc[e];
    __syncthreads();
    for (int s = 1; s < 256; s <<= 1) {
        int v[8];
        if (tid >= s) {
#pragma unroll
            for (int e = 0; e < 8; e++) v[e] = hist[tid - s][e];
        }
        __syncthreads();
        if (tid >= s) {
#pragma unroll
            for (int e = 0; e < 8; e++) hist[tid][e] += v[e];
        }
        __syncthreads();
    }
    int myBase[8];
#pragma unroll
    for (int e = 0; e < 8; e++) myBase[e] = hist[tid][e] - lc[e];
    if (tid == 0) {
        int off = 0;
#pragma unroll
        for (int e = 0; e < 8; e++) {
            int c = hist[255][e];
            counts[e] = c;
            offsets[e] = off; offs[e] = off;
            off += (c + 127) & ~127;
        }
    }
    __syncthreads();
    int cur[8];
#pragma unroll
    for (int e = 0; e < 8; e++) cur[e] = myBase[e];
#pragma unroll
    for (int j = 0; j < 16; j++) {
        int e = le[j];
        int s_ = offs[e] + cur[e]++;
        slot[base + j] = s_;
        tok[s_] = base + j;
    }
    double ps[8] = {0, 0, 0, 0, 0, 0, 0, 0};
    for (int t = tid; t < T_TOK; t += 256) {
#pragma unroll
        for (int e = 0; e < 8; e++) ps[e] += (double)probs[(size_t)t * 8 + e];
    }
#pragma unroll
    for (int e = 0; e < 8; e++) red[tid][e] = ps[e];
    __syncthreads();
    for (int s = 128; s > 0; s >>= 1) {
        if (tid < s) {
#pragma unroll
            for (int e = 0; e < 8; e++) red[tid][e] += red[tid + s][e];
        }
        __syncthreads();
    }
    if (tid == 0) {
        double aux = 0.0;
#pragma unroll
        for (int e = 0; e < 8; e++)
            aux += ((double)hist[255][e] / T_TOK) * (red[0][e] / T_TOK);
        auxout[0] = (float)(aux * NEXP);
    }
}

// ---------------- gather: x -> bf16 at precomputed slot ----------------------
__global__ __launch_bounds__(256) void gather_k(const float* __restrict__ x,
                                                const int* __restrict__ slot,
                                                ushort* __restrict__ xg)
{
    int tid = threadIdx.x, w = tid >> 6, lane = tid & 63;
    int t = blockIdx.x * 4 + w;
    int s = slot[t];
    const float4* xr = (const float4*)(x + (size_t)t * DIM);
    ushort4* xo = (ushort4*)(xg + (size_t)s * DIM);
#pragma unroll
    for (int q = 0; q < 4; q++) {
        float4 v = xr[q * 64 + lane];
        ushort4 b;
        b.x = f2bf(v.x); b.y = f2bf(v.y); b.z = f2bf(v.z); b.w = f2bf(v.w);
        xo[q * 64 + lane] = b;
    }
}

// -------- materialize W_fc[e][j*1024+o][k*256+l] = sum_i A[i,j,k]*S[i,o,l] ---
__global__ __launch_bounds__(256) void wfc_k(const float* __restrict__ A,
                                             const float* __restrict__ S,
                                             ushort* __restrict__ W)
{
    int b = blockIdx.x;
    int e = b >> 10, o = b & 1023;
    int l = threadIdx.x;
    __shared__ float Ash[64];
    if (l < 64) Ash[l] = A[e * 64 + l];
    __syncthreads();
    float s0 = S[((size_t)(e * 4 + 0) * 1024 + o) * 256 + l];
    float s1 = S[((size_t)(e * 4 + 1) * 1024 + o) * 256 + l];
    float s2 = S[((size_t)(e * 4 + 2) * 1024 + o) * 256 + l];
    float s3 = S[((size_t)(e * 4 + 3) * 1024 + o) * 256 + l];
    size_t base = (size_t)e * 4194304ull;
#pragma unroll
    for (int j = 0; j < 4; j++)
#pragma unroll
        for (int k = 0; k < 4; k++) {
            float v = Ash[j * 4 + k] * s0 + Ash[16 + j * 4 + k] * s1 +
                      Ash[32 + j * 4 + k] * s2 + Ash[48 + j * 4 + k] * s3;
            W[base + (size_t)(j * 1024 + o) * 1024 + k * 256 + l] = f2bf(v);
        }
}

// ------- materialize W_proj[e][j*256+o][k*1024+l] = sum_i A[i,j,k]*S[i,o,l] --
__global__ __launch_bounds__(256) void wpj_k(const float* __restrict__ A,
                                             const float* __restrict__ S,
                                             ushort* __restrict__ W)
{
    int b = blockIdx.x;
    int e = b >> 8, o = b & 255;
    int tid = threadIdx.x;
    __shared__ float Ash[64];
    if (tid < 64) Ash[tid] = A[e * 64 + tid];
    __syncthreads();
    float s[4][4];
#pragma unroll
    for (int i = 0; i < 4; i++)
#pragma unroll
        for (int q = 0; q < 4; q++)
            s[i][q] = S[((size_t)(e * 4 + i) * 256 + o) * 1024 + q * 256 + tid];
    size_t base = (size_t)e * 4194304ull;
#pragma unroll
    for (int j = 0; j < 4; j++)
#pragma unroll
        for (int k = 0; k < 4; k++) {
            float a0 = Ash[j * 4 + k], a1 = Ash[16 + j * 4 + k];
            float a2 = Ash[32 + j * 4 + k], a3 = Ash[48 + j * 4 + k];
#pragma unroll
            for (int q = 0; q < 4; q++) {
                float v = a0 * s[0][q] + a1 * s[1][q] + a2 * s[2][q] + a3 * s[3][q];
                W[base + (size_t)(j * 256 + o) * 4096 + k * 1024 + q * 256 + tid] = f2bf(v);
            }
        }
}

// ---------------- MFMA GEMM: C[m,n] = sum_k A[m,k] * W[n,k]  (B^T layout) ----
// m97 structure: 128x128 tile, BK=64, single 32KB LDS buffer, 2 barriers/K-step
// (cross-block implicit overlap; needs >=3 resident blocks/CU). XOR-swizzled
// LDS via pre-swizzled GLOBAL source (rule 21). NSPLIT: split-K; each split
// writes f32 partials P[split]. XCD-grouped decode: b&7 owns fixed N-panels.
template <int KDIM, int NDIM, int NSPLIT, bool FC>
__global__ __launch_bounds__(256, 4) void moe_gemm_k(const ushort* __restrict__ Abuf,
                                                     const ushort* __restrict__ Wbuf,
                                                     ushort* __restrict__ Hout,
                                                     float* __restrict__ Yout,
                                                     const int* __restrict__ counts,
                                                     const int* __restrict__ offsets)
{
    __shared__ __align__(16) ushort As[128 * 64];
    __shared__ __align__(16) ushort Bs[128 * 64];
    constexpr int NBY = NDIM / 128;
    constexpr int YPX = NBY / 8;              // N-panels per XCD
    constexpr int KSUB = KDIM / NSPLIT;
    constexpr int NT = KSUB / 64;
    int b = blockIdx.x;
    int r = b >> 3;
    int nb = (b & 7) * YPX + r / (40 * NSPLIT);
    int rem = r % (40 * NSPLIT);
    int split = rem / 40;
    int ms = rem % 40;
    int e = -1, mt = 0, acct = 0;
#pragma unroll
    for (int i = 0; i < 8; i++) {
        int tiles = (counts[i] + 127) >> 7;
        if (e < 0 && ms < acct + tiles) { e = i; mt = ms - acct; }
        acct += tiles;
    }
    if (e < 0) return;
    int m_base = offsets[e] + mt * 128;
    int n_base = nb * 128;
    int tid = threadIdx.x, w = tid >> 6, lane = tid & 63;
    int wm = w >> 1, wn = w & 1;
    const ushort* Ab = Abuf + (size_t)m_base * KDIM + split * KSUB;
    const ushort* Bb = Wbuf + (size_t)e * NDIM * KDIM + (size_t)n_base * KDIM + split * KSUB;
    int lr = lane >> 3;                        // staging row within 8-row group
    int lcs = (((lane & 7) ^ lr) << 3);        // swizzled source chunk (ushorts)
    f32x4 acc[4][4];
#pragma unroll
    for (int i = 0; i < 4; i++)
#pragma unroll
        for (int j = 0; j < 4; j++) acc[i][j] = (f32x4){0.f, 0.f, 0.f, 0.f};

    for (int t = 0; t < NT; t++) {
        int k0 = t * 64;
#pragma unroll
        for (int i = 0; i < 4; i++) {
            int r0 = i * 32 + w * 8;
            gload_lds16(Ab + (size_t)(r0 + lr) * KDIM + k0 + lcs, As + r0 * 64);
            gload_lds16(Bb + (size_t)(r0 + lr) * KDIM + k0 + lcs, Bs + r0 * 64);
        }
        __syncthreads();
#pragma unroll
        for (int ks = 0; ks < 2; ks++) {
            short8 a[4], bfr[4];
#pragma unroll
            for (int f = 0; f < 4; f++) {
                int ra = wm * 64 + f * 16 + (lane & 15);
                int ca = (((ks * 4 + (lane >> 4)) ^ (lane & 7)) << 3);
                a[f] = *(const short8*)&As[ra * 64 + ca];
                int rb = wn * 64 + f * 16 + (lane & 15);
                bfr[f] = *(const short8*)&Bs[rb * 64 + ca];
            }
#pragma unroll
            for (int mf = 0; mf < 4; mf++)
#pragma unroll
                for (int nf = 0; nf < 4; nf++)
                    acc[mf][nf] = __builtin_amdgcn_mfma_f32_16x16x32_bf16(a[mf], bfr[nf], acc[mf][nf], 0, 0, 0);
        }
        __syncthreads();
    }

    int col0 = n_base + wn * 64;
    int row0 = wm * 64 + (lane >> 4) * 4;   // C/D: col=lane&15, row=(lane>>4)*4+reg
    if (FC) {
#pragma unroll
        for (int mf = 0; mf < 4; mf++)
#pragma unroll
            for (int nf = 0; nf < 4; nf++) {
                int col = col0 + nf * 16 + (lane & 15);
#pragma unroll
                for (int rg = 0; rg < 4; rg++) {
                    float v = acc[mf][nf][rg];
                    v = v >= 0.f ? v : 0.5f * v;   // leaky relu slope 0.5
                    v = v * v;                     // square
                    Hout[(size_t)(m_base + row0 + mf * 16 + rg) * NDIM + col] = f2bf(v);
                }
            }
    } else {
        float* P = Yout + (size_t)split * SLOTS * NDIM;
#pragma unroll
        for (int mf = 0; mf < 4; mf++)
#pragma unroll
            for (int nf = 0; nf < 4; nf++) {
                int col = col0 + nf * 16 + (lane & 15);
#pragma unroll
                for (int rg = 0; rg < 4; rg++)
                    P[(size_t)(m_base + row0 + mf * 16 + rg) * NDIM + col] = acc[mf][nf][rg];
            }
    }
}

// -------- reduce: out[tok[slot]] = P0[slot] + P1[slot] (valid slots) ---------
__global__ __launch_bounds__(256) void reduce_k(const float* __restrict__ P,
                                                const int* __restrict__ tok,
                                                float* __restrict__ out)
{
    int slot = blockIdx.x;
    int t = tok[slot];
    if (t < 0) return;
    const float4* p0 = (const float4*)(P + (size_t)slot * DIM);
    const float4* p1 = (const float4*)(P + (size_t)(SLOTS + slot) * DIM);
    float4* o = (float4*)(out + (size_t)t * DIM);
    int i = threadIdx.x;
    float4 a = p0[i], b = p1[i];
    o[i] = (float4){a.x + b.x, a.y + b.y, a.z + b.z, a.w + b.w};
}

extern "C" void kernel_launch(void* const* d_in, const int* in_sizes, int n_in,
                              void* d_out, int out_size, void* d_ws, size_t ws_size,
                              hipStream_t stream)
{
    const float* x    = (const float*)d_in[0];
    const float* wr   = (const float*)d_in[1];
    const float* A_fc = (const float*)d_in[2];
    const float* S_fc = (const float*)d_in[3];
    const float* A_pj = (const float*)d_in[4];
    const float* S_pj = (const float*)d_in[5];
    float* out = (float*)d_out;
    char* ws = (char*)d_ws;

    ushort* Wfc   = (ushort*)(ws + OFF_WFC);
    float*  Part  = (float*)(ws + OFF_WFC);    // aliases W_fc (dead after fc GEMM)
    ushort* Wpj   = (ushort*)(ws + OFF_WPROJ);
    ushort* xg    = (ushort*)(ws + OFF_XG);
    ushort* h     = (ushort*)(ws + OFF_H);
    float*  probs = (float*)(ws + OFF_PROBS);
    int*    eidx  = (int*)(ws + OFF_EIDX);
    int*    tok   = (int*)(ws + OFF_TOK);
    int*    counts  = (int*)(ws + OFF_CNT);
    int*    offsets = counts + 16;
    int*    slot  = (int*)(ws + OFF_SLOT);

    router_k<<<T_TOK / 4, 256, 0, stream>>>(x, wr, probs, eidx);
    plan_k<<<1, 256, 0, stream>>>(probs, eidx, counts, offsets, slot, tok,
                                  out + (size_t)T_TOK * DIM);
    gather_k<<<T_TOK / 4, 256, 0, stream>>>(x, slot, xg);
    wfc_k<<<NEXP * 1024, 256, 0, stream>>>(A_fc, S_fc, Wfc);
    wpj_k<<<NEXP * 256, 256, 0, stream>>>(A_pj, S_pj, Wpj);
    // fc: 40 m-tiles x 32 n-panels, no split -> 1280 blocks (~4-5/CU resident)
    moe_gemm_k<1024, 4096, 1, true><<<1280, 256, 0, stream>>>(xg, Wfc, h, nullptr, counts, offsets);
    // proj: 40 m-tiles x 8 n-panels x split-K 2 -> 640 blocks, f32 partials
    moe_gemm_k<4096, 1024, 2, false><<<640, 256, 0, stream>>>(h, Wpj, nullptr, Part, counts, offsets);
    reduce_k<<<SLOTS, 256, 0, stream>>>(Part, tok, out);
}

// Round 5
// 190.913 us; speedup vs baseline: 2.7072x; 1.0730x over previous
//
#include <hip/hip_runtime.h>
#include <hip/hip_bf16.h>

// MoE PHM MLP, MI355X. B=2,S=2048,D=1024 -> T=4096 tokens; E=8, N=4, HID=4096.
// router(f64, writes bf16 x copy) -> plan -> W_eff materialization (bf16) ->
// fc GEMM (128x256 tile, indirect A rows via tok[], epilogue leaky^2) ->
// proj GEMM (128x256, split-K=2 -> f32 partials) -> reduce+scatter.
//
// Workspace (~187 MiB):
//   [0,64MiB)    W_fc bf16 [E][4096][1024]; dead after fc GEMM -> reused for
//                proj partials P[2][5120][1024] f32 (42 MiB).
//   [64,128MiB)  W_proj bf16 [E][1024][4096]
//   xb bf16 [4096][1024] (token-order), h bf16 [5120][4096], probs, eidx, tok, counts

#define T_TOK 4096
#define DIM   1024
#define NEXP  8
#define HIDD  4096
#define SLOTS 5120

static constexpr size_t OFF_WFC   = 0;
static constexpr size_t OFF_WPROJ = 67108864ull;
static constexpr size_t OFF_XB    = 134217728ull;
static constexpr size_t OFF_H     = 144703488ull;
static constexpr size_t OFF_PROBS = 186646528ull;
static constexpr size_t OFF_EIDX  = OFF_PROBS + (size_t)T_TOK*8*4;
static constexpr size_t OFF_TOK   = OFF_EIDX + (size_t)T_TOK*4;
static constexpr size_t OFF_CNT   = OFF_TOK + (size_t)SLOTS*4;

typedef __attribute__((ext_vector_type(8))) short short8;
typedef __attribute__((ext_vector_type(4))) float f32x4;

static __device__ __forceinline__ ushort f2bf(float f) {
    __hip_bfloat16 h = __float2bfloat16(f);
    return __builtin_bit_cast(ushort, h);
}

static __device__ __forceinline__ void gload_lds16(const ushort* g, ushort* l) {
    __builtin_amdgcn_global_load_lds((const __attribute__((address_space(1))) void*)g,
                                     (__attribute__((address_space(3))) void*)l,
                                     16, 0, 0);
}

// ------- router: f64 logits, softmax probs, argmax, bf16 x copy (token order)
__global__ __launch_bounds__(256) void router_k(const float* __restrict__ x,
                                                const float* __restrict__ wr,
                                                float* __restrict__ probs,
                                                int* __restrict__ eidx,
                                                ushort* __restrict__ xb)
{
    int tid = threadIdx.x, w = tid >> 6, lane = tid & 63;
    int t = blockIdx.x * 4 + w;
    const float4* xr = (const float4*)(x + (size_t)t * DIM);
    float4 xv[4];
#pragma unroll
    for (int q = 0; q < 4; q++) xv[q] = xr[q * 64 + lane];
    // bf16 copy for the fc GEMM's indirect A staging
    ushort4* xo = (ushort4*)(xb + (size_t)t * DIM);
#pragma unroll
    for (int q = 0; q < 4; q++) {
        float4 v = xv[q];
        ushort4 bq;
        bq.x = f2bf(v.x); bq.y = f2bf(v.y); bq.z = f2bf(v.z); bq.w = f2bf(v.w);
        xo[q * 64 + lane] = bq;
    }
    double lg[8];
#pragma unroll
    for (int e = 0; e < 8; e++) {
        const float4* wv = (const float4*)(wr + (size_t)e * DIM);
        double s = 0.0;
#pragma unroll
        for (int q = 0; q < 4; q++) {
            float4 a = xv[q], b = wv[q * 64 + lane];
            s += (double)a.x * b.x + (double)a.y * b.y + (double)a.z * b.z + (double)a.w * b.w;
        }
#pragma unroll
        for (int d = 1; d < 64; d <<= 1) s += __shfl_xor(s, d);
        lg[e] = s;
    }
    double m = lg[0];
#pragma unroll
    for (int e = 1; e < 8; e++) m = lg[e] > m ? lg[e] : m;
    double ex[8], sum = 0.0;
#pragma unroll
    for (int e = 0; e < 8; e++) { ex[e] = exp(lg[e] - m); sum += ex[e]; }
    if (lane < 8) probs[(size_t)t * 8 + lane] = (float)(ex[lane] / sum);
    if (lane == 0) {
        int am = 0; double bv = lg[0];
#pragma unroll
        for (int e = 1; e < 8; e++) if (lg[e] > bv) { bv = lg[e]; am = e; }  // first-max = jnp.argmax
        eidx[t] = am;
    }
}

// --- plan: single block. tok=-1 init, histogram, stable rank, offsets, aux ---
__global__ __launch_bounds__(256) void plan_k(const float* __restrict__ probs,
                                              const int* __restrict__ eidx,
                                              int* __restrict__ counts,
                                              int* __restrict__ offsets,
                                              int* __restrict__ tok,
                                              float* __restrict__ auxout)
{
    __shared__ int hist[256][8];
    __shared__ double red[256][8];
    __shared__ int offs[8];
    int tid = threadIdx.x;
    for (int i = tid; i < SLOTS; i += 256) tok[i] = -1;
    int base = tid * 16;
    int le[16];
    int lc[8] = {0,0,0,0,0,0,0,0};
#pragma unroll
    for (int j = 0; j < 16; j++) { le[j] = eidx[base + j]; lc[le[j]]++; }
#pragma unroll
    for (int e = 0; e < 8; e++) hist[tid][e] = lc[e];
    __syncthreads();
    for (int s = 1; s < 256; s <<= 1) {
        int v[8];
        if (tid >= s) {
#pragma unroll
            for (int e = 0; e < 8; e++) v[e] = hist[tid - s][e];
        }
        __syncthreads();
        if (tid >= s) {
#pragma unroll
            for (int e = 0; e < 8; e++) hist[tid][e] += v[e];
        }
        __syncthreads();
    }
    int myBase[8];
#pragma unroll
    for (int e = 0; e < 8; e++) myBase[e] = hist[tid][e] - lc[e];
    if (tid == 0) {
        int off = 0;
#pragma unroll
        for (int e = 0; e < 8; e++) {
            int c = hist[255][e];
            counts[e] = c;
            offsets[e] = off; offs[e] = off;
            off += (c + 127) & ~127;
        }
    }
    __syncthreads();
    int cur[8];
#pragma unroll
    for (int e = 0; e < 8; e++) cur[e] = myBase[e];
#pragma unroll
    for (int j = 0; j < 16; j++) {
        int e = le[j];
        tok[offs[e] + cur[e]++] = base + j;
    }
    double ps[8] = {0, 0, 0, 0, 0, 0, 0, 0};
    for (int t = tid; t < T_TOK; t += 256) {
#pragma unroll
        for (int e = 0; e < 8; e++) ps[e] += (double)probs[(size_t)t * 8 + e];
    }
#pragma unroll
    for (int e = 0; e < 8; e++) red[tid][e] = ps[e];
    __syncthreads();
    for (int s = 128; s > 0; s >>= 1) {
        if (tid < s) {
#pragma unroll
            for (int e = 0; e < 8; e++) red[tid][e] += red[tid + s][e];
        }
        __syncthreads();
    }
    if (tid == 0) {
        double aux = 0.0;
#pragma unroll
        for (int e = 0; e < 8; e++)
            aux += ((double)hist[255][e] / T_TOK) * (red[0][e] / T_TOK);
        auxout[0] = (float)(aux * NEXP);
    }
}

// -------- materialize W_fc[e][j*1024+o][k*256+l] = sum_i A[i,j,k]*S[i,o,l] ---
__global__ __launch_bounds__(256) void wfc_k(const float* __restrict__ A,
                                             const float* __restrict__ S,
                                             ushort* __restrict__ W)
{
    int b = blockIdx.x;
    int e = b >> 10, o = b & 1023;
    int l = threadIdx.x;
    __shared__ float Ash[64];
    if (l < 64) Ash[l] = A[e * 64 + l];
    __syncthreads();
    float s0 = S[((size_t)(e * 4 + 0) * 1024 + o) * 256 + l];
    float s1 = S[((size_t)(e * 4 + 1) * 1024 + o) * 256 + l];
    float s2 = S[((size_t)(e * 4 + 2) * 1024 + o) * 256 + l];
    float s3 = S[((size_t)(e * 4 + 3) * 1024 + o) * 256 + l];
    size_t base = (size_t)e * 4194304ull;
#pragma unroll
    for (int j = 0; j < 4; j++)
#pragma unroll
        for (int k = 0; k < 4; k++) {
            float v = Ash[j * 4 + k] * s0 + Ash[16 + j * 4 + k] * s1 +
                      Ash[32 + j * 4 + k] * s2 + Ash[48 + j * 4 + k] * s3;
            W[base + (size_t)(j * 1024 + o) * 1024 + k * 256 + l] = f2bf(v);
        }
}

// ------- materialize W_proj[e][j*256+o][k*1024+l] = sum_i A[i,j,k]*S[i,o,l] --
__global__ __launch_bounds__(256) void wpj_k(const float* __restrict__ A,
                                             const float* __restrict__ S,
                                             ushort* __restrict__ W)
{
    int b = blockIdx.x;
    int e = b >> 8, o = b & 255;
    int tid = threadIdx.x;
    __shared__ float Ash[64];
    if (tid < 64) Ash[tid] = A[e * 64 + tid];
    __syncthreads();
    float s[4][4];
#pragma unroll
    for (int i = 0; i < 4; i++)
#pragma unroll
        for (int q = 0; q < 4; q++)
            s[i][q] = S[((size_t)(e * 4 + i) * 256 + o) * 1024 + q * 256 + tid];
    size_t base = (size_t)e * 4194304ull;
#pragma unroll
    for (int j = 0; j < 4; j++)
#pragma unroll
        for (int k = 0; k < 4; k++) {
            float a0 = Ash[j * 4 + k], a1 = Ash[16 + j * 4 + k];
            float a2 = Ash[32 + j * 4 + k], a3 = Ash[48 + j * 4 + k];
#pragma unroll
            for (int q = 0; q < 4; q++) {
                float v = a0 * s[0][q] + a1 * s[1][q] + a2 * s[2][q] + a3 * s[3][q];
                W[base + (size_t)(j * 256 + o) * 4096 + k * 1024 + q * 256 + tid] = f2bf(v);
            }
        }
}

// ---------------- MFMA GEMM: C[m,n] = sum_k A[m,k] * W[n,k]  (B^T layout) ----
// 128x256 tile, BK=64, 4 waves (2x2: 64m x 128n each, acc 4x8), single-buffer
// 48KB LDS, 2 barriers/K-step (m97 structure). XOR-swizzled LDS via
// pre-swizzled GLOBAL source. FC: A rows indirected through tok[] (reads
// token-order xb). NSPLIT: split-K, f32 partials. XCD-grouped block decode.
template <int KDIM, int NDIM, int NSPLIT, bool FC>
__global__ __launch_bounds__(256, 2) void moe_gemm_k(const ushort* __restrict__ Abuf,
                                                     const ushort* __restrict__ Wbuf,
                                                     ushort* __restrict__ Hout,
                                                     float* __restrict__ Yout,
                                                     const int* __restrict__ counts,
                                                     const int* __restrict__ offsets,
                                                     const int* __restrict__ tok)
{
    __shared__ __align__(16) ushort As[128 * 64];
    __shared__ __align__(16) ushort Bs[256 * 64];
    constexpr int KSUB = KDIM / NSPLIT;
    constexpr int NT = KSUB / 64;
    int b = blockIdx.x;
    int nb, split, ms;
    if (FC) {               // grid 640: 16 n-panels, YPX=2 per XCD
        int r = b >> 3;
        nb = (b & 7) * 2 + r / 40;
        split = 0;
        ms = r % 40;
    } else {                // grid 320: 4 n-panels x 2 splits = 8 combos = XCD
        nb = (b & 7) >> 1;
        split = b & 1;
        ms = b >> 3;
    }
    int e = -1, mt = 0, acct = 0;
#pragma unroll
    for (int i = 0; i < 8; i++) {
        int tiles = (counts[i] + 127) >> 7;
        if (e < 0 && ms < acct + tiles) { e = i; mt = ms - acct; }
        acct += tiles;
    }
    if (e < 0) return;
    int m_base = offsets[e] + mt * 128;
    int n_base = nb * 256;
    int tid = threadIdx.x, w = tid >> 6, lane = tid & 63;
    int wm = w >> 1, wn = w & 1;
    const ushort* Bb = Wbuf + (size_t)e * NDIM * KDIM + (size_t)n_base * KDIM;
    int lr = lane >> 3;                        // staging row within 8-row group
    int lcs = (((lane & 7) ^ lr) << 3);        // swizzled source chunk (ushorts)
    // A-row source pointers (fixed across K): fc indirects through tok[]
    const ushort* arow[4];
#pragma unroll
    for (int i = 0; i < 4; i++) {
        int sl = m_base + i * 32 + w * 8 + lr;
        int rt = sl;
        if (FC) { rt = tok[sl]; if (rt < 0) rt = 0; }
        arow[i] = Abuf + (size_t)rt * KDIM + lcs;
    }
    f32x4 acc[4][8];
#pragma unroll
    for (int i = 0; i < 4; i++)
#pragma unroll
        for (int j = 0; j < 8; j++) acc[i][j] = (f32x4){0.f, 0.f, 0.f, 0.f};

    for (int t = 0; t < NT; t++) {
        int k0 = split * KSUB + t * 64;
#pragma unroll
        for (int i = 0; i < 4; i++)
            gload_lds16(arow[i] + k0, &As[(i * 32 + w * 8) * 64]);
#pragma unroll
        for (int i = 0; i < 8; i++) {
            int r0 = i * 32 + w * 8;
            gload_lds16(Bb + (size_t)(r0 + lr) * KDIM + k0 + lcs, &Bs[r0 * 64]);
        }
        __syncthreads();
#pragma unroll
        for (int ks = 0; ks < 2; ks++) {
            short8 a[4], bfr[8];
#pragma unroll
            for (int f = 0; f < 4; f++) {
                int ra = wm * 64 + f * 16 + (lane & 15);
                int ca = (((ks * 4 + (lane >> 4)) ^ (lane & 7)) << 3);
                a[f] = *(const short8*)&As[ra * 64 + ca];
            }
#pragma unroll
            for (int f = 0; f < 8; f++) {
                int rb = wn * 128 + f * 16 + (lane & 15);
                int ca = (((ks * 4 + (lane >> 4)) ^ (lane & 7)) << 3);
                bfr[f] = *(const short8*)&Bs[rb * 64 + ca];
            }
#pragma unroll
            for (int mf = 0; mf < 4; mf++)
#pragma unroll
                for (int nf = 0; nf < 8; nf++)
                    acc[mf][nf] = __builtin_amdgcn_mfma_f32_16x16x32_bf16(a[mf], bfr[nf], acc[mf][nf], 0, 0, 0);
        }
        __syncthreads();
    }

    int col0 = n_base + wn * 128;
    int row0 = wm * 64 + (lane >> 4) * 4;   // C/D: col=lane&15, row=(lane>>4)*4+reg
    if (FC) {
#pragma unroll
        for (int mf = 0; mf < 4; mf++)
#pragma unroll
            for (int nf = 0; nf < 8; nf++) {
                int col = col0 + nf * 16 + (lane & 15);
#pragma unroll
                for (int rg = 0; rg < 4; rg++) {
                    float v = acc[mf][nf][rg];
                    v = v >= 0.f ? v : 0.5f * v;   // leaky relu slope 0.5
                    v = v * v;                     // square
                    Hout[(size_t)(m_base + row0 + mf * 16 + rg) * NDIM + col] = f2bf(v);
                }
            }
    } else {
        float* P = Yout + (size_t)split * SLOTS * NDIM;
#pragma unroll
        for (int mf = 0; mf < 4; mf++)
#pragma unroll
            for (int nf = 0; nf < 8; nf++) {
                int col = col0 + nf * 16 + (lane & 15);
#pragma unroll
                for (int rg = 0; rg < 4; rg++)
                    P[(size_t)(m_base + row0 + mf * 16 + rg) * NDIM + col] = acc[mf][nf][rg];
            }
    }
}

// -------- reduce: out[tok[slot]] = P0[slot] + P1[slot] (valid slots) ---------
__global__ __launch_bounds__(256) void reduce_k(const float* __restrict__ P,
                                                const int* __restrict__ tok,
                                                float* __restrict__ out)
{
    int slot = blockIdx.x;
    int t = tok[slot];
    if (t < 0) return;
    const float4* p0 = (const float4*)(P + (size_t)slot * DIM);
    const float4* p1 = (const float4*)(P + (size_t)(SLOTS + slot) * DIM);
    float4* o = (float4*)(out + (size_t)t * DIM);
    int i = threadIdx.x;
    float4 a = p0[i], b = p1[i];
    o[i] = (float4){a.x + b.x, a.y + b.y, a.z + b.z, a.w + b.w};
}

extern "C" void kernel_launch(void* const* d_in, const int* in_sizes, int n_in,
                              void* d_out, int out_size, void* d_ws, size_t ws_size,
                              hipStream_t stream)
{
    const float* x    = (const float*)d_in[0];
    const float* wr   = (const float*)d_in[1];
    const float* A_fc = (const float*)d_in[2];
    const float* S_fc = (const float*)d_in[3];
    const float* A_pj = (const float*)d_in[4];
    const float* S_pj = (const float*)d_in[5];
    float* out = (float*)d_out;
    char* ws = (char*)d_ws;

    ushort* Wfc   = (ushort*)(ws + OFF_WFC);
    float*  Part  = (float*)(ws + OFF_WFC);    // aliases W_fc (dead after fc GEMM)
    ushort* Wpj   = (ushort*)(ws + OFF_WPROJ);
    ushort* xb    = (ushort*)(ws + OFF_XB);
    ushort* h     = (ushort*)(ws + OFF_H);
    float*  probs = (float*)(ws + OFF_PROBS);
    int*    eidx  = (int*)(ws + OFF_EIDX);
    int*    tok   = (int*)(ws + OFF_TOK);
    int*    counts  = (int*)(ws + OFF_CNT);
    int*    offsets = counts + 16;

    router_k<<<T_TOK / 4, 256, 0, stream>>>(x, wr, probs, eidx, xb);
    plan_k<<<1, 256, 0, stream>>>(probs, eidx, counts, offsets, tok,
                                  out + (size_t)T_TOK * DIM);
    wfc_k<<<NEXP * 1024, 256, 0, stream>>>(A_fc, S_fc, Wfc);
    wpj_k<<<NEXP * 256, 256, 0, stream>>>(A_pj, S_pj, Wpj);
    // fc: 40 m-tiles x 16 n-panels (256 wide) -> 640 blocks, indirect A
    moe_gemm_k<1024, 4096, 1, true><<<640, 256, 0, stream>>>(xb, Wfc, h, nullptr, counts, offsets, tok);
    // proj: 40 m-tiles x 4 n-panels x split-K 2 -> 320 blocks, f32 partials
    moe_gemm_k<4096, 1024, 2, false><<<320, 256, 0, stream>>>(h, Wpj, nullptr, Part, counts, offsets, tok);
    reduce_k<<<SLOTS, 256, 0, stream>>>(Part, tok, out);
}